// Round 9
// baseline (980.508 us; speedup 1.0000x reference)
//
#include <hip/hip_runtime.h>
#include <math.h>

// GatedDeltaNet forward, MI355X round 11: scan_mfma dg-pair variant.
// The round-10 producer-consumer scan failed twice (treated as
// kernel-implicated); this takes the same latency-hiding goal via a
// LOW-RISK route: 128 blocks x 512 threads, waves 0-3 run d-group even,
// waves 4-7 run d-group odd — two independent instances of the PROVEN
// round-9 4-wave schedule sharing the staged Wm/Qd/W2/KdT tiles
// (dg-invariant). Identical barrier pattern/slot parity to round 9;
// per-dg sS/sMidT copies (LDS 133.5 KB). 2 waves/SIMD hide each other's
// latency; staging amortized over 2x compute (FETCH halves).
// GEMM (256^2 2-phase), prep_chunks (MFMA P3), conv/epilogue unchanged.
// B=2 L=4096 D=2048 H=16 Dh=128 C=64 KW=4
#define B_   2
#define L_   4096
#define D_   2048
#define H_   16
#define DH   128
#define CH   64
#define NCH  64
#define HD   2048
#define BH   32
#define BHL  131072
#define PSZ  16777216ull

typedef unsigned short u16;
typedef __attribute__((ext_vector_type(8))) short bf16x8;
typedef __attribute__((ext_vector_type(4))) float f32x4;
#define MFMA16(a, b, c) __builtin_amdgcn_mfma_f32_16x16x32_bf16(a, b, c, 0, 0, 0)

static __device__ __forceinline__ float sigm(float x) { return 1.0f / (1.0f + expf(-x)); }

static __device__ __forceinline__ float b2f(u16 u) {
    union { float f; unsigned int i; } v; v.i = ((unsigned int)u) << 16; return v.f;
}
static __device__ __forceinline__ u16 f2b(float f) {
    union { float f; unsigned int i; } v; v.f = f;
    unsigned int r = v.i + 0x7fffu + ((v.i >> 16) & 1u);
    return (u16)(r >> 16);
}
static __device__ __forceinline__ void b8ld(const u16* p, float* d) {
    uint4 u = *(const uint4*)p;
    d[0] = b2f((u16)(u.x & 0xffff)); d[1] = b2f((u16)(u.x >> 16));
    d[2] = b2f((u16)(u.y & 0xffff)); d[3] = b2f((u16)(u.y >> 16));
    d[4] = b2f((u16)(u.z & 0xffff)); d[5] = b2f((u16)(u.z >> 16));
    d[6] = b2f((u16)(u.w & 0xffff)); d[7] = b2f((u16)(u.w >> 16));
}
static __device__ __forceinline__ void b8st(const float* s, u16* p) {
    uint4 u;
    u.x = (unsigned)f2b(s[0]) | ((unsigned)f2b(s[1]) << 16);
    u.y = (unsigned)f2b(s[2]) | ((unsigned)f2b(s[3]) << 16);
    u.z = (unsigned)f2b(s[4]) | ((unsigned)f2b(s[5]) << 16);
    u.w = (unsigned)f2b(s[6]) | ((unsigned)f2b(s[7]) << 16);
    *(uint4*)p = u;
}
static __device__ __forceinline__ void cstore(float* p, float v) { *p = v; }
static __device__ __forceinline__ void cstore(u16* p, float v) { *p = f2b(v); }

// async 16B global -> LDS (dest = wave-uniform base + lane*16; our layouts are
// lane-consecutive by construction; global source may be per-lane swizzled)
static __device__ __forceinline__ void async16(const u16* g, u16* l) {
    __builtin_amdgcn_global_load_lds(
        (const __attribute__((address_space(1))) unsigned int*)g,
        (__attribute__((address_space(3))) unsigned int*)l, 16, 0, 0);
}

// manual barriers (rule #18: sched_barrier after waits)
static __device__ __forceinline__ void bar_lgkm() {
    asm volatile("s_waitcnt lgkmcnt(0)" ::: "memory");
    __builtin_amdgcn_sched_barrier(0);
    __builtin_amdgcn_s_barrier();
    __builtin_amdgcn_sched_barrier(0);
}
static __device__ __forceinline__ void wait_vm0() {
    asm volatile("s_waitcnt vmcnt(0)" ::: "memory");
    __builtin_amdgcn_sched_barrier(0);
}

// fp32 -> bf16 bulk convert (n multiple of 8; one 8-elt group per thread)
__global__ __launch_bounds__(256) void cvt_f2b(const float* __restrict__ in,
                                               u16* __restrict__ out, int n8) {
    int i = blockIdx.x * 256 + threadIdx.x;
    if (i >= n8) return;
    float t[8];
    float4 a = *(const float4*)(in + (size_t)i * 8);
    float4 b = *(const float4*)(in + (size_t)i * 8 + 4);
    t[0] = a.x; t[1] = a.y; t[2] = a.z; t[3] = a.w;
    t[4] = b.x; t[5] = b.y; t[6] = b.z; t[7] = b.w;
    b8st(t, out + (size_t)i * 8);
}

// ---------------------------------------------------------------------------
// 256x256-tile double-buffered 2-phase MFMA GEMM (unchanged from round 9).
// ---------------------------------------------------------------------------
template <typename TC>
__global__ __launch_bounds__(512) void gemm_bt_async(const u16* __restrict__ A,
                                                     const u16* __restrict__ Bm,
                                                     TC* __restrict__ Cm,
                                                     int M, int N, int K) {
    __shared__ __align__(16) u16 sA[2][256 * 64];
    __shared__ __align__(16) u16 sB[2][256 * 64];
    const int tid = threadIdx.x;
    const int w = tid >> 6, lane = tid & 63, lq = lane >> 4, ln = lane & 15;
    const int wm = w >> 2, wn = w & 3;
    const int nx = gridDim.x;
    const int lin = blockIdx.y * nx + blockIdx.x;
    const int chunk = (nx * gridDim.y) >> 3;
    const int wg = (lin & 7) * chunk + (lin >> 3);
    const int mbase = (wg / nx) * 256, nbase = (wg % nx) * 256;

    f32x4 acc[8][4];
#pragma unroll
    for (int mt = 0; mt < 8; mt++)
#pragma unroll
        for (int nt = 0; nt < 4; nt++) acc[mt][nt] = (f32x4){0.f, 0.f, 0.f, 0.f};

    auto stage = [&](int kt, int p) {
        const int k0 = kt * 64;
#pragma unroll
        for (int j = 0; j < 4; j++) {
            int c = tid + 512 * j;                 // chunk 0..2047
            int row = c >> 3;
            int oct = (c & 7) ^ (row & 7);         // swizzled source octet
            async16(A + (size_t)(mbase + row) * K + k0 + oct * 8, &sA[p][c * 8]);
            async16(Bm + (size_t)(nbase + row) * K + k0 + oct * 8, &sB[p][c * 8]);
        }
    };

    const int NT = K >> 6;
    stage(0, 0);
    wait_vm0();
    __builtin_amdgcn_s_barrier();
    __builtin_amdgcn_sched_barrier(0);

    for (int t = 0; t < NT; t++) {
        const int p = t & 1;
        if (t + 1 < NT) stage(t + 1, p ^ 1);       // prefetch overlaps compute
        __builtin_amdgcn_s_setprio(1);
#pragma unroll
        for (int ks = 0; ks < 2; ks++) {
            const int o = ks * 4 + lq;
            bf16x8 bfr[4];
#pragma unroll
            for (int nt = 0; nt < 4; nt++) {
                int nn = wn * 64 + nt * 16 + ln;
                bfr[nt] = *(const bf16x8*)&sB[p][(nn << 6) + ((o ^ (nn & 7)) << 3)];
            }
#pragma unroll
            for (int mt = 0; mt < 8; mt++) {
                int m = wm * 128 + mt * 16 + ln;
                bf16x8 af = *(const bf16x8*)&sA[p][(m << 6) + ((o ^ (m & 7)) << 3)];
#pragma unroll
                for (int nt = 0; nt < 4; nt++)
                    acc[mt][nt] = MFMA16(af, bfr[nt], acc[mt][nt]);
            }
        }
        __builtin_amdgcn_s_setprio(0);
        if (t + 1 < NT) {
            wait_vm0();        // next tile arrived (hidden under the MFMAs)
            bar_lgkm();        // all waves done reading buf p; next tile visible
        }
    }
#pragma unroll
    for (int mt = 0; mt < 8; mt++)
#pragma unroll
        for (int nt = 0; nt < 4; nt++) {
            int col = nbase + wn * 64 + nt * 16 + ln;
#pragma unroll
            for (int r = 0; r < 4; r++) {
                int row = mbase + wm * 128 + mt * 16 + lq * 4 + r;
                cstore(Cm + (size_t)row * N + col, acc[mt][nt][r]);
            }
        }
}

// ---------------------------------------------------------------------------
// Causal depthwise conv (KW=4) + SiLU + optional L2 norm over Dh.
// ---------------------------------------------------------------------------
__global__ __launch_bounds__(256) void conv_silu_norm(const u16* __restrict__ pre,
                                                      const float* __restrict__ w,
                                                      u16* __restrict__ out, int mode) {
    int wid = blockIdx.x * 4 + (threadIdx.x >> 6);
    int lane = threadIdx.x & 63;
    int l = wid & (L_ - 1);
    int bh = wid >> 12;
    int b = bh >> 4, h = bh & 15;

    float vals[2];
    float sumsq = 0.0f;
#pragma unroll
    for (int s = 0; s < 2; s++) {
        int d = lane + 64 * s;
        int c = h * DH + d;
        const u16* col = pre + (size_t)b * L_ * HD + c;
        float acc = 0.0f;
        if (l >= 3) {
            acc = w[c * 4 + 0] * b2f(col[(size_t)(l - 3) * HD]) +
                  w[c * 4 + 1] * b2f(col[(size_t)(l - 2) * HD]) +
                  w[c * 4 + 2] * b2f(col[(size_t)(l - 1) * HD]) +
                  w[c * 4 + 3] * b2f(col[(size_t)l * HD]);
        } else {
#pragma unroll
            for (int j = 0; j < 4; j++) {
                int ll = l - 3 + j;
                if (ll >= 0) acc += w[c * 4 + j] * b2f(col[(size_t)ll * HD]);
            }
        }
        float y = acc * sigm(acc);
        vals[s] = y;
        sumsq += y * y;
    }
    if (mode < 2) {
#pragma unroll
        for (int m = 32; m >= 1; m >>= 1) sumsq += __shfl_xor(sumsq, m, 64);
        float scale = 1.0f / fmaxf(sqrtf(sumsq), 1e-12f);
        if (mode == 0) scale *= 0.08838834764831843f;
        vals[0] *= scale;
        vals[1] *= scale;
    }
    u16* o = out + ((size_t)bh * L_ + l) * DH;
    o[lane] = f2b(vals[0]);
    o[lane + 64] = f2b(vals[1]);
}

__global__ __launch_bounds__(64) void proj_small(const float* __restrict__ x,
                                                 const float* __restrict__ Wb,
                                                 const float* __restrict__ Wa,
                                                 float* __restrict__ bpre,
                                                 float* __restrict__ apre) {
    int row = blockIdx.x;
    int lane = threadIdx.x;
    const float* xr = x + (size_t)row * D_;
    float xv[32];
#pragma unroll
    for (int j = 0; j < 32; j++) xv[j] = xr[lane + 64 * j];
    for (int h = 0; h < 16; h++) {
        const float* wr = Wb + (size_t)h * D_;
        float acc = 0.0f;
#pragma unroll
        for (int j = 0; j < 32; j++) acc += xv[j] * wr[lane + 64 * j];
#pragma unroll
        for (int m = 32; m >= 1; m >>= 1) acc += __shfl_xor(acc, m, 64);
        if (lane == 0) bpre[(size_t)row * 16 + h] = acc;
    }
    for (int h = 0; h < 16; h++) {
        const float* wr = Wa + (size_t)h * D_;
        float acc = 0.0f;
#pragma unroll
        for (int j = 0; j < 32; j++) acc += xv[j] * wr[lane + 64 * j];
#pragma unroll
        for (int m = 32; m >= 1; m >>= 1) acc += __shfl_xor(acc, m, 64);
        if (lane == 0) apre[(size_t)row * 16 + h] = acc;
    }
}

__global__ __launch_bounds__(256) void beta_g_k(const float* __restrict__ bpre,
                                                const float* __restrict__ apre,
                                                const float* __restrict__ A_log,
                                                const float* __restrict__ dt_bias,
                                                float* __restrict__ beta, float* __restrict__ g) {
    int gi = blockIdx.x * 256 + threadIdx.x;
    int l = gi & (L_ - 1);
    int bh = gi >> 12;
    int b = bh >> 4, h = bh & 15;
    float bp = bpre[((size_t)b * L_ + l) * 16 + h];
    float ap = apre[((size_t)b * L_ + l) * 16 + h] + dt_bias[h];
    float sp = (ap > 20.0f) ? ap : log1pf(expf(ap));
    beta[(size_t)bh * L_ + l] = 1.0f / (1.0f + expf(-bp));
    g[(size_t)bh * L_ + l] = -expf(A_log[h]) * sp;
}

// ---------------------------------------------------------------------------
// Per-chunk prep (2048 blocks, 4 waves). Unchanged from round 8.
// ---------------------------------------------------------------------------
__global__ __launch_bounds__(256) void prep_chunks(u16* __restrict__ q, u16* __restrict__ k,
                                                   u16* __restrict__ v,
                                                   const float* __restrict__ beta,
                                                   const float* __restrict__ g,
                                                   u16* __restrict__ Wm, u16* __restrict__ W2,
                                                   float* __restrict__ gamC) {
    __shared__ __align__(16) u16 sKb[64 * 136];   // raw K (bf16) -> later V
    __shared__ __align__(16) float sA[64 * 65];   // masked A -> later VsT (u16 128x64)
    __shared__ __align__(16) float sT[64 * 68];   // T fp32 -> later Thi/Tlo (u16 2x4096)
    __shared__ __align__(16) u16 sKsT[128 * 64];  // βγK^T, octet-swizzled
    __shared__ float sLg[CH], sGam[CH], sGcr[CH], sBeta[CH];

    u16* sVsT = (u16*)sA;                          // alias (dead after P2b)
    u16* sThi = (u16*)sT;                          // alias (after snapshot)
    u16* sTlo = (u16*)sT + 4096;

    const int cid = blockIdx.x;
    const int bh = cid >> 6, n = cid & 63;
    const int tid = threadIdx.x;
    const int w = tid >> 6, lane = tid & 63, lq = lane >> 4, ln = lane & 15;
    const size_t cbase = ((size_t)bh * L_ + (size_t)n * CH) * DH;
    u16* qw = q + cbase;
    u16* kw = k + cbase;
    u16* vc = v + cbase;

    // ---- P0: Q fragment prefetch + K staging + cumsum ----
    bf16x8 aQ[4];
    {
        const u16* qrow = qw + (size_t)(w * 16 + ln) * DH;
#pragma unroll
        for (int ks = 0; ks < 4; ks++)
            aQ[ks] = *(const bf16x8*)(qrow + ks * 32 + lq * 8);
    }
#pragma unroll
    for (int rep = 0; rep < 4; rep++) {
        int f = tid + 256 * rep;                   // 1024 chunks of 8 u16
        int row = f >> 4, c8 = (f & 15) * 8;
        *(uint4*)&sKb[row * 136 + c8] = *(const uint4*)(kw + (size_t)row * DH + c8);
    }
    if (tid < 64) {
        float lg = g[(size_t)bh * L_ + (size_t)n * CH + tid];
#pragma unroll
        for (int off = 1; off < 64; off <<= 1) {
            float u = __shfl_up(lg, off, 64);
            if (tid >= off) lg += u;
        }
        float lgC = __shfl(lg, 63, 64);
        sLg[tid] = lg;
        sGam[tid] = expf(lg);
        sGcr[tid] = expf(lgC - lg);
        sBeta[tid] = beta[(size_t)bh * L_ + (size_t)n * CH + tid];
        if (tid == 63) gamC[cid] = expf(lgC);
    }
    __syncthreads();

    // ---- P1: MFMA A/Qd + mask/write; zero sT ----
    {
        f32x4 accA[4], accQ[4];
#pragma unroll
        for (int nt = 0; nt < 4; nt++) {
            accA[nt] = (f32x4){0.f, 0.f, 0.f, 0.f};
            accQ[nt] = (f32x4){0.f, 0.f, 0.f, 0.f};
        }
#pragma unroll
        for (int ks = 0; ks < 4; ks++) {
            int k0 = ks * 32 + lq * 8;
            bf16x8 aK = *(const bf16x8*)&sKb[(w * 16 + ln) * 136 + k0];
#pragma unroll
            for (int nt = 0; nt < 4; nt++) {
                bf16x8 bK = *(const bf16x8*)&sKb[(nt * 16 + ln) * 136 + k0];
                accA[nt] = MFMA16(aK, bK, accA[nt]);
                accQ[nt] = MFMA16(aQ[ks], bK, accQ[nt]);
            }
        }
        for (int idx = tid; idx < 64 * 68; idx += 256) sT[idx] = 0.f;
        u16* w2c = W2 + (size_t)cid * CH * CH;
#pragma unroll
        for (int nt = 0; nt < 4; nt++) {
            int j = nt * 16 + ln;
            float lgj = sLg[j];
#pragma unroll
            for (int r = 0; r < 4; r++) {
                int i = w * 16 + lq * 4 + r;
                float dexp = expf(fminf(sLg[i] - lgj, 0.f));  // valid for j<=i; clamped else
                sA[i * 65 + j] = (j < i) ? sBeta[i] * dexp * accA[nt][r] : 0.f;
                w2c[i * CH + j] = f2b((j <= i) ? accQ[nt][r] * dexp : 0.f);
            }
        }
    }
    __syncthreads();

    // ---- P2a: per-wave diagonal 16x16 inversion (registers) + q scale + KdT ----
    float colv[16];   // lane ln holds column ln of Dinv for wave w's block
    {
        const int i0 = w * 16;
        colv[0] = (ln == 0) ? 1.f : 0.f;
#pragma unroll
        for (int i = 1; i < 16; i++) {
            float acc = (ln == i) ? 1.f : 0.f;
#pragma unroll
            for (int kk = 0; kk < 15; kk++) {
                if (kk < i) acc -= sA[(i0 + i) * 65 + i0 + kk] * colv[kk];
            }
            colv[i] = acc;
        }
    }
#pragma unroll
    for (int rep = 0; rep < 4; rep++) {            // q *= γ (global RMW)
        int f = tid + 256 * rep;
        int i = f >> 4, d8 = (f & 15) * 8;
        float tq[8];
        b8ld(qw + (size_t)i * DH + d8, tq);
        float sq = sGam[i];
#pragma unroll
        for (int jj = 0; jj < 8; jj++) tq[jj] *= sq;
        b8st(tq, qw + (size_t)i * DH + d8);
    }
    // KdT: k chunk region rewritten in place as [e=0..127][i-octets swizzled].
    {
        int e = tid >> 1, qh = tid & 1;
#pragma unroll
        for (int oo = 0; oo < 4; oo++) {
            int i0 = qh * 32 + oo * 8;
            u16 op[8];
#pragma unroll
            for (int jj = 0; jj < 8; jj++)
                op[jj] = f2b(b2f(sKb[(i0 + jj) * 136 + e]) * sGcr[i0 + jj]);
            int slot = ((i0 >> 3) ^ (e & 7));
            uint4 pk;
            pk.x = (unsigned)op[0] | ((unsigned)op[1] << 16);
            pk.y = (unsigned)op[2] | ((unsigned)op[3] << 16);
            pk.z = (unsigned)op[4] | ((unsigned)op[5] << 16);
            pk.w = (unsigned)op[6] | ((unsigned)op[7] << 16);
            *(uint4*)(kw + e * 64 + slot * 8) = pk;
        }
    }
    if (lq == 0) {
#pragma unroll
        for (int i = 0; i < 16; i++) sT[(w * 16 + i) * 68 + w * 16 + ln] = colv[i];
    }
    __syncthreads();

    // ---- P2b: blocked forward substitution, T_ij = -Dinv_i * sum A_ik T_kj ----
    auto trijob = [&](int bi, int bj) {
        float accv[4] = {0.f, 0.f, 0.f, 0.f};      // Ssum[lq*4+r][ln]
        for (int kb = bj; kb < bi; kb++) {
#pragma unroll
            for (int kk = 0; kk < 16; kk++) {
                float bv = sT[(kb * 16 + kk) * 68 + bj * 16 + ln];
#pragma unroll
                for (int r = 0; r < 4; r++)
                    accv[r] += sA[(bi * 16 + lq * 4 + r) * 65 + kb * 16 + kk] * bv;
            }
        }
        float xv[4] = {0.f, 0.f, 0.f, 0.f};
#pragma unroll
        for (int kk = 0; kk < 16; kk++) {
            // Ssum[kk][ln] lives in lane (kk>>2)*16+ln, register kk&3
            float bv = __shfl(accv[kk & 3], (kk >> 2) * 16 + ln, 64);
#pragma unroll
            for (int r = 0; r < 4; r++)
                xv[r] -= sT[(bi * 16 + lq * 4 + r) * 68 + bi * 16 + kk] * bv;
        }
#pragma unroll
        for (int r = 0; r < 4; r++)
            sT[(bi * 16 + lq * 4 + r) * 68 + bj * 16 + ln] = xv[r];
    };
    if (w < 3) trijob(w + 1, w);
    __syncthreads();
    if (w < 2) trijob(w + 2, w);
    __syncthreads();
    if (w == 0) trijob(3, 0);
    __syncthreads();

    // ---- P3 (MFMA): Wm = T @ (βγK), U = T @ (βV) ----
    // (a) KsT[e][kk] = β[kk]γ[kk]K[kk][e], octet-swizzled rows (stride 64)
    {
        int e = tid >> 1, qh = tid & 1;
#pragma unroll
        for (int oo = 0; oo < 4; oo++) {
            int i0 = qh * 32 + oo * 8;
            u16 op[8];
#pragma unroll
            for (int jj = 0; jj < 8; jj++) {
                int kkw = i0 + jj;
                op[jj] = f2b(b2f(sKb[kkw * 136 + e]) * (sBeta[kkw] * sGam[kkw]));
            }
            int slot = ((i0 >> 3) ^ (e & 7));
            uint4 pk;
            pk.x = (unsigned)op[0] | ((unsigned)op[1] << 16);
            pk.y = (unsigned)op[2] | ((unsigned)op[3] << 16);
            pk.z = (unsigned)op[4] | ((unsigned)op[5] << 16);
            pk.w = (unsigned)op[6] | ((unsigned)op[7] << 16);
            *(uint4*)&sKsT[e * 64 + slot * 8] = pk;
        }
    }
    // (b) snapshot T rows to registers (16 f32/thread) before in-place cvt
    float tvs[16];
    {
        int ti = tid >> 2, kks = (tid & 3) * 16;
#pragma unroll
        for (int j = 0; j < 16; j++) tvs[j] = sT[ti * 68 + kks + j];
    }
    __syncthreads();   // KsT built (sKb reads done); all sT reads done

    // (c) write Thi/Tlo (octet-swizzled, stride 64) into sT's space
    {
        int ti = tid >> 2, kks = (tid & 3) * 16;
#pragma unroll
        for (int h = 0; h < 2; h++) {
            u16 hi8[8], lo8[8];
#pragma unroll
            for (int j = 0; j < 8; j++) {
                float tv = tvs[h * 8 + j];
                u16 hb = f2b(tv);
                hi8[j] = hb;
                lo8[j] = f2b(tv - b2f(hb));
            }
            int io = (kks >> 3) + h;
            int slot = io ^ (ti & 7);
            uint4 ph, pl;
            ph.x = (unsigned)hi8[0] | ((unsigned)hi8[1] << 16);
            ph.y = (unsigned)hi8[2] | ((unsigned)hi8[3] << 16);
            ph.z = (unsigned)hi8[4] | ((unsigned)hi8[5] << 16);
            ph.w = (unsigned)hi8[6] | ((unsigned)hi8[7] << 16);
            pl.x = (unsigned)lo8[0] | ((unsigned)lo8[1] << 16);
            pl.y = (unsigned)lo8[2] | ((unsigned)lo8[3] << 16);
            pl.z = (unsigned)lo8[4] | ((unsigned)lo8[5] << 16);
            pl.w = (unsigned)lo8[6] | ((unsigned)lo8[7] << 16);
            *(uint4*)&sThi[ti * 64 + slot * 8] = ph;
            *(uint4*)&sTlo[ti * 64 + slot * 8] = pl;
        }
    }
    // (d) stage V rows into sKb's space (K is dead now)
#pragma unroll
    for (int rep = 0; rep < 4; rep++) {
        int f = tid + 256 * rep;
        int row = f >> 4, c8 = (f & 15) * 8;
        *(uint4*)&sKb[row * 136 + c8] = *(const uint4*)(vc + (size_t)row * DH + c8);
    }
    __syncthreads();   // Thi/Tlo + V staged

    // (e) VsT[e][kk] = β[kk]V[kk][e] into sA's space
    {
        int e = tid >> 1, qh = tid & 1;
#pragma unroll
        for (int oo = 0; oo < 4; oo++) {
            int i0 = qh * 32 + oo * 8;
            u16 op[8];
#pragma unroll
            for (int jj = 0; jj < 8; jj++) {
                int kkw = i0 + jj;
                op[jj] = f2b(b2f(sKb[kkw * 136 + e]) * sBeta[kkw]);
            }
            int slot = ((i0 >> 3) ^ (e & 7));
            uint4 pk;
            pk.x = (unsigned)op[0] | ((unsigned)op[1] << 16);
            pk.y = (unsigned)op[2] | ((unsigned)op[3] << 16);
            pk.z = (unsigned)op[4] | ((unsigned)op[5] << 16);
            pk.w = (unsigned)op[6] | ((unsigned)op[7] << 16);
            *(uint4*)&sVsT[e * 64 + slot * 8] = pk;
        }
    }
    __syncthreads();

    // (f) MFMA: wave w owns output cols e in [w*32, w*32+32)
    {
        u16* wmc = Wm + (size_t)cid * CH * DH;
        bf16x8 bK[2][2], bV[2][2];   // [et][ks]
#pragma unroll
        for (int et = 0; et < 2; et++) {
            int eb = w * 32 + et * 16 + ln;
#pragma unroll
            for (int ks = 0; ks < 2; ks++) {
                int o = ks * 4 + lq;
                bK[et][ks] = *(const bf16x8*)&sKsT[eb * 64 + ((o ^ (eb & 7)) << 3)];
                bV[et][ks] = *(const bf16x8*)&sVsT[eb * 64 + ((o ^ (eb & 7)) << 3)];
            }
        }
#pragma unroll
        for (int it = 0; it < 4; it++) {
            int ia = it * 16 + ln;
            bf16x8 ahi[2], alo[2];
#pragma unroll
            for (int ks = 0; ks < 2; ks++) {
                int o = ks * 4 + lq;
                ahi[ks] = *(const bf16x8*)&sThi[ia * 64 + ((o ^ (ia & 7)) << 3)];
                alo[ks] = *(const bf16x8*)&sTlo[ia * 64 + ((o ^ (ia & 7)) << 3)];
            }
#pragma unroll
            for (int et = 0; et < 2; et++) {
                f32x4 aK = (f32x4){0.f, 0.f, 0.f, 0.f};
                f32x4 aV = (f32x4){0.f, 0.f, 0.f, 0.f};
#pragma unroll
                for (int ks = 0; ks < 2; ks++) {
                    aK = MFMA16(ahi[ks], bK[et][ks], aK);
                    aK = MFMA16(alo[ks], bK[et][ks], aK);
                    aV = MFMA16(ahi[ks], bV[et][ks], aV);
                    aV = MFMA16(alo[ks], bV[et][ks], aV);
                }
                int ecol = w * 32 + et * 16 + ln;
#pragma unroll
                for (int r = 0; r < 4; r++) {
                    int irow = it * 16 + lq * 4 + r;
                    wmc[(size_t)irow * DH + ecol] = f2b(aK[r]);
                    vc[(size_t)irow * DH + ecol] = f2b(aV[r]);
                }
            }
        }
    }
}

// ---------------------------------------------------------------------------
// MFMA inter-chunk scan, dg-pair (128 blocks = BH * 4 dg-pairs, 512 threads).
// Waves 0-3 run d-group d0, waves 4-7 run d-group d0+16 — two independent
// copies of the round-9 schedule sharing staged Wm/Qd/W2/KdT tiles.
// ---------------------------------------------------------------------------
__global__ __launch_bounds__(512) void scan_mfma(const u16* __restrict__ Wm,
                                                 const u16* __restrict__ U,
                                                 const u16* __restrict__ Qd,
                                                 const u16* __restrict__ Kd,
                                                 const u16* __restrict__ W2,
                                                 const float* __restrict__ gamC,
                                                 const float* __restrict__ S0,
                                                 float* __restrict__ Og,
                                                 float* __restrict__ Sfin) {
    __shared__ __align__(16) u16 sWm[2][64 * 128];
    __shared__ __align__(16) u16 sQd[2][64 * 128];
    __shared__ __align__(16) u16 sW2[2][64 * 64];
    __shared__ __align__(16) u16 sKdT[2][128 * 64];
    __shared__ __align__(16) u16 sS[2][2][16 * 136];   // [dgrp][buf]
    __shared__ __align__(16) u16 sMidT[2][16 * 72];    // [dgrp]

    const int bid = blockIdx.x;
    // XCD swizzle: the 4 dg-pair blocks of one head share bid%8 (one XCD)
    const int xcd = bid & 7, slot = bid >> 3;          // slot 0..15
    const int bh = xcd + 8 * (slot >> 2);              // 32 heads
    const int tid = threadIdx.x;
    const int w = tid >> 6, lane = tid & 63, lq = lane >> 4, ln = lane & 15;
    const int dgrp = w >> 2, wp = w & 3;               // dg instance + local wave
    const int d0 = (slot & 3) * 32 + dgrp * 16;

    f32x4 S_t[2];
#pragma unroll
    for (int t2 = 0; t2 < 2; t2++)
#pragma unroll
        for (int r = 0; r < 4; r++)
            S_t[t2][r] = S0[(size_t)bh * DH * DH + (size_t)(d0 + lq * 4 + r) * DH + wp * 32 + t2 * 16 + ln];

    // async stage of chunk m tiles into buffer p (all 512 threads)
    auto stage_async = [&](int m, int p) {
        const size_t cid2 = (size_t)bh * NCH + m;
        const u16* wmc = Wm + cid2 * CH * DH;
        const size_t tb = ((size_t)bh * L_ + (size_t)m * CH) * DH;
        const u16* qc  = Qd + tb;
        const u16* kc  = Kd + tb;                  // pre-transposed+swizzled
        const u16* w2c = W2 + cid2 * CH * CH;
#pragma unroll
        for (int j = 0; j < 2; j++) {
            int c = tid + 512 * j;                  // 16B chunk 0..1023
            int row = c >> 4;
            int osrc = (c & 15) ^ (row & 7);        // pre-swizzled source octet
            async16(wmc + (size_t)row * DH + osrc * 8, &sWm[p][c * 8]);
            async16(qc  + (size_t)row * DH + osrc * 8, &sQd[p][c * 8]);
            async16(kc + (size_t)c * 8, &sKdT[p][c * 8]);   // linear copy
        }
        {
            int c = tid;                            // 0..511
            int row = c >> 3;
            int osrc = (c & 7) ^ (row & 7);
            async16(w2c + (size_t)row * CH + osrc * 8, &sW2[p][c * 8]);
        }
    };
    auto write_ss = [&](int p) {
#pragma unroll
        for (int t2 = 0; t2 < 2; t2++)
#pragma unroll
            for (int r = 0; r < 4; r++)
                sS[dgrp][p][(lq * 4 + r) * 136 + wp * 32 + t2 * 16 + ln] = f2b(S_t[t2][r]);
    };

    u16 ureg[4], uregN[4];
    auto load_ureg = [&](int m, u16* dst) {
        const u16* uc = U + ((size_t)bh * L_ + (size_t)m * CH) * DH;
#pragma unroll
        for (int r = 0; r < 4; r++)
            dst[r] = uc[(size_t)(wp * 16 + lq * 4 + r) * DH + d0 + ln];
    };

    // ---- prologue: chunk 0 into buffer 0 ----
    stage_async(0, 0);
    load_ureg(0, ureg);
    float gCur = gamC[(size_t)bh * NCH];
    float gNext = 0.f;
    write_ss(0);
    wait_vm0();
    bar_lgkm();

    for (int n = 0; n < NCH; n++) {
        const int p = n & 1;
        const bool hasN = (n + 1 < NCH);
        if (hasN) {
            stage_async(n + 1, p ^ 1);
            load_ureg(n + 1, uregN);
            gNext = gamC[(size_t)bh * NCH + n + 1];
        }

        // G1: mid = U - Wm @ S^T
        {
            f32x4 macc = (f32x4){0.f, 0.f, 0.f, 0.f};
            const int i = wp * 16 + ln;
#pragma unroll
            for (int ks = 0; ks < 4; ks++) {
                int o = ks * 4 + lq;
                bf16x8 a = *(const bf16x8*)&sWm[p][i * 128 + ((o ^ (i & 7)) << 3)];
                bf16x8 b = *(const bf16x8*)&sS[dgrp][p][ln * 136 + ks * 32 + lq * 8];
                macc = MFMA16(a, b, macc);
            }
#pragma unroll
            for (int r = 0; r < 4; r++) {
                int ii = wp * 16 + lq * 4 + r;
                float mv = b2f(ureg[r]) - macc[r];
                sMidT[dgrp][ln * 72 + ii] = f2b(mv);
            }
        }
        bar_lgkm();   // lgkm-only: async prefetch stays in flight

        // G2: O = Qd @ S^T + W2 @ mid
        {
            f32x4 oacc = (f32x4){0.f, 0.f, 0.f, 0.f};
            const int i = wp * 16 + ln;
#pragma unroll
            for (int ks = 0; ks < 4; ks++) {
                int o = ks * 4 + lq;
                bf16x8 a = *(const bf16x8*)&sQd[p][i * 128 + ((o ^ (i & 7)) << 3)];
                bf16x8 b = *(const bf16x8*)&sS[dgrp][p][ln * 136 + ks * 32 + lq * 8];
                oacc = MFMA16(a, b, oacc);
            }
#pragma unroll
            for (int ks = 0; ks < 2; ks++) {
                int o = ks * 4 + lq;
                bf16x8 a = *(const bf16x8*)&sW2[p][i * 64 + ((o ^ (i & 7)) << 3)];
                bf16x8 b = *(const bf16x8*)&sMidT[dgrp][ln * 72 + ks * 32 + lq * 8];
                oacc = MFMA16(a, b, oacc);
            }
#pragma unroll
            for (int r = 0; r < 4; r++) {
                int ii = wp * 16 + lq * 4 + r;
                Og[((size_t)bh * L_ + (size_t)n * CH + ii) * DH + d0 + ln] = oacc[r];
            }
        }

        // G3: S = gC*S + mid^T @ Kd
#pragma unroll
        for (int t2 = 0; t2 < 2; t2++)
#pragma unroll
            for (int r = 0; r < 4; r++) S_t[t2][r] *= gCur;
#pragma unroll
        for (int ks = 0; ks < 2; ks++) {
            bf16x8 a = *(const bf16x8*)&sMidT[dgrp][ln * 72 + ks * 32 + lq * 8];
#pragma unroll
            for (int t2 = 0; t2 < 2; t2++) {
                int e = (2 * wp + t2) * 16 + ln;
                int o = ks * 4 + lq;
                bf16x8 b = *(const bf16x8*)&sKdT[p][e * 64 + ((o ^ (e & 7)) << 3)];
                S_t[t2] = MFMA16(a, b, S_t[t2]);
            }
        }

        if (hasN) {
            write_ss(p ^ 1);         // ds writes overlap the vm drain below
#pragma unroll
            for (int r = 0; r < 4; r++) ureg[r] = uregN[r];
            gCur = gNext;
            wait_vm0();              // staged tiles + ureg arrived
            bar_lgkm();              // next-iter tiles visible to all waves
        }
    }

#pragma unroll
    for (int t2 = 0; t2 < 2; t2++)
#pragma unroll
        for (int r = 0; r < 4; r++)
            Sfin[(size_t)bh * DH * DH + (size_t)(d0 + lq * 4 + r) * DH + wp * 32 + t2 * 16 + ln] = S_t[t2][r];
}

__global__ __launch_bounds__(256) void epilogue_gate(const float* __restrict__ Ob,
                                                     const u16* __restrict__ gpre,
                                                     const float* __restrict__ norm_w,
                                                     u16* __restrict__ gated) {
    int wid = blockIdx.x * 4 + (threadIdx.x >> 6);
    int lane = threadIdx.x & 63;
    int l = wid & (L_ - 1);
    int bh = wid >> 12;
    int b = bh >> 4, h = bh & 15;
    const float* orow = Ob + ((size_t)bh * L_ + l) * DH;
    float o0 = orow[lane], o1 = orow[lane + 64];
    float ss = o0 * o0 + o1 * o1;
#pragma unroll
    for (int m = 32; m >= 1; m >>= 1) ss += __shfl_xor(ss, m, 64);
    float r = rsqrtf(ss * (1.0f / 128.0f) + 1e-5f);
    size_t gidx = ((size_t)b * L_ + l) * HD + h * DH;
    float gp0 = b2f(gpre[gidx + lane]), gp1 = b2f(gpre[gidx + lane + 64]);
    gated[gidx + lane] = f2b(o0 * r * norm_w[lane] * (gp0 * sigm(gp0)));
    gated[gidx + lane + 64] = f2b(o1 * r * norm_w[lane + 64] * (gp1 * sigm(gp1)));
}

// ---------------------------------------------------------------------------
extern "C" void kernel_launch(void* const* d_in, const int* in_sizes, int n_in,
                              void* d_out, int out_size, void* d_ws, size_t ws_size,
                              hipStream_t stream) {
    const float* x       = (const float*)d_in[0];
    const float* Wq      = (const float*)d_in[1];
    const float* Wk      = (const float*)d_in[2];
    const float* Wv      = (const float*)d_in[3];
    const float* Wb      = (const float*)d_in[4];
    const float* Wa      = (const float*)d_in[5];
    const float* A_log   = (const float*)d_in[6];
    const float* dt_bias = (const float*)d_in[7];
    const float* conv_q  = (const float*)d_in[8];
    const float* conv_k  = (const float*)d_in[9];
    const float* conv_v  = (const float*)d_in[10];
    const float* Wg      = (const float*)d_in[11];
    const float* norm_w  = (const float*)d_in[12];
    const float* Wo      = (const float*)d_in[13];
    const float* S0      = (const float*)d_in[14];
    float* out = (float*)d_out;

    // Workspace (~195 MB, u16 units):
    //   Pb (preact scratch -> Wm), Qb (q->Qd), Kb (k->KdT -> gated),
    //   Vb (v->U -> gpre), W2b, xb (bf16 x), wbuf (rotating bf16 weight).
    // O (fp32) lives in d_out[0:PSZ]; Sfin in d_out[PSZ:].
    u16* Pb = (u16*)d_ws;
    u16* Qb = Pb + PSZ;
    u16* Kb = Qb + PSZ;
    u16* Vb = Kb + PSZ;
    u16* W2b = Vb + PSZ;                        // PSZ/2 u16
    u16* xb  = W2b + PSZ / 2;                   // PSZ u16
    u16* wbuf = xb + PSZ;                       // 2048*2048 u16
    float* bpre = (float*)(wbuf + 4194304);
    float* apre = bpre + BHL;
    float* betab = apre + BHL;
    float* gbuf = betab + BHL;
    float* gamC = gbuf + BHL;                   // 2048

    float* Obuf = out;
    float* Sfin = out + PSZ;

    dim3 gblk(8, 32);   // (N/256, M/256) for M=8192,N=2048; 256 blocks
    const int W8 = 2048 * 2048 / 8;             // weight cvt groups

    cvt_f2b<<<8192, 256, 0, stream>>>(x, xb, (int)(PSZ / 8));
    cvt_f2b<<<2048, 256, 0, stream>>>(Wq, wbuf, W8);
    gemm_bt_async<u16><<<gblk, 512, 0, stream>>>(xb, wbuf, Pb, 8192, 2048, 2048);
    conv_silu_norm<<<32768, 256, 0, stream>>>(Pb, conv_q, Qb, 0);
    cvt_f2b<<<2048, 256, 0, stream>>>(Wk, wbuf, W8);
    gemm_bt_async<u16><<<gblk, 512, 0, stream>>>(xb, wbuf, Pb, 8192, 2048, 2048);
    conv_silu_norm<<<32768, 256, 0, stream>>>(Pb, conv_k, Kb, 1);
    cvt_f2b<<<2048, 256, 0, stream>>>(Wv, wbuf, W8);
    gemm_bt_async<u16><<<gblk, 512, 0, stream>>>(xb, wbuf, Pb, 8192, 2048, 2048);
    conv_silu_norm<<<32768, 256, 0, stream>>>(Pb, conv_v, Vb, 2);
    proj_small<<<8192, 64, 0, stream>>>(x, Wb, Wa, bpre, apre);
    beta_g_k<<<512, 256, 0, stream>>>(bpre, apre, A_log, dt_bias, betab, gbuf);
    prep_chunks<<<2048, 256, 0, stream>>>(Qb, Kb, Vb, betab, gbuf, Pb, W2b, gamC);
    scan_mfma<<<128, 512, 0, stream>>>(Pb, Vb, Qb, Kb, W2b, gamC, S0, Obuf, Sfin);
    // g projection after the scan: gpre reuses Vb (U is dead now)
    cvt_f2b<<<2048, 256, 0, stream>>>(Wg, wbuf, W8);
    gemm_bt_async<u16><<<gblk, 512, 0, stream>>>(xb, wbuf, Vb, 8192, 2048, 2048);
    epilogue_gate<<<32768, 256, 0, stream>>>(Obuf, Vb, norm_w, Kb);
    cvt_f2b<<<2048, 256, 0, stream>>>(Wo, wbuf, W8);
    gemm_bt_async<float><<<gblk, 512, 0, stream>>>(Kb, wbuf, out, 8192, 2048, 2048);
}

// Round 10
// 959.272 us; speedup vs baseline: 1.0221x; 1.0221x over previous
//
#include <hip/hip_runtime.h>
#include <math.h>

// GatedDeltaNet forward, MI355X round 12: scan reverted to the measured
// round-9 structure (256 blocks x 4 waves; dg-pair was a measured
// regression — half the CUs idle) with a sync-free critical-path cut:
// G2's Qd@S^T is independent of mid, so it runs in phase A interleaved
// with G1's Wm@S^T (dual MFMA chains, shared sS fragment reads); phase B
// is just W2@mid + store + G3. Identical barriers/buffers to round 9.
// proj_small: 4 waves/block (2048 blocks) instead of 1-wave blocks.
// GEMM (256^2 2-phase), prep_chunks (MFMA P3), conv/epilogue unchanged.
// B=2 L=4096 D=2048 H=16 Dh=128 C=64 KW=4
#define B_   2
#define L_   4096
#define D_   2048
#define H_   16
#define DH   128
#define CH   64
#define NCH  64
#define HD   2048
#define BH   32
#define BHL  131072
#define PSZ  16777216ull

typedef unsigned short u16;
typedef __attribute__((ext_vector_type(8))) short bf16x8;
typedef __attribute__((ext_vector_type(4))) float f32x4;
#define MFMA16(a, b, c) __builtin_amdgcn_mfma_f32_16x16x32_bf16(a, b, c, 0, 0, 0)

static __device__ __forceinline__ float sigm(float x) { return 1.0f / (1.0f + expf(-x)); }

static __device__ __forceinline__ float b2f(u16 u) {
    union { float f; unsigned int i; } v; v.i = ((unsigned int)u) << 16; return v.f;
}
static __device__ __forceinline__ u16 f2b(float f) {
    union { float f; unsigned int i; } v; v.f = f;
    unsigned int r = v.i + 0x7fffu + ((v.i >> 16) & 1u);
    return (u16)(r >> 16);
}
static __device__ __forceinline__ void b8ld(const u16* p, float* d) {
    uint4 u = *(const uint4*)p;
    d[0] = b2f((u16)(u.x & 0xffff)); d[1] = b2f((u16)(u.x >> 16));
    d[2] = b2f((u16)(u.y & 0xffff)); d[3] = b2f((u16)(u.y >> 16));
    d[4] = b2f((u16)(u.z & 0xffff)); d[5] = b2f((u16)(u.z >> 16));
    d[6] = b2f((u16)(u.w & 0xffff)); d[7] = b2f((u16)(u.w >> 16));
}
static __device__ __forceinline__ void b8st(const float* s, u16* p) {
    uint4 u;
    u.x = (unsigned)f2b(s[0]) | ((unsigned)f2b(s[1]) << 16);
    u.y = (unsigned)f2b(s[2]) | ((unsigned)f2b(s[3]) << 16);
    u.z = (unsigned)f2b(s[4]) | ((unsigned)f2b(s[5]) << 16);
    u.w = (unsigned)f2b(s[6]) | ((unsigned)f2b(s[7]) << 16);
    *(uint4*)p = u;
}
static __device__ __forceinline__ void cstore(float* p, float v) { *p = v; }
static __device__ __forceinline__ void cstore(u16* p, float v) { *p = f2b(v); }

// async 16B global -> LDS (dest = wave-uniform base + lane*16; our layouts are
// lane-consecutive by construction; global source may be per-lane swizzled)
static __device__ __forceinline__ void async16(const u16* g, u16* l) {
    __builtin_amdgcn_global_load_lds(
        (const __attribute__((address_space(1))) unsigned int*)g,
        (__attribute__((address_space(3))) unsigned int*)l, 16, 0, 0);
}

// manual barriers (rule #18: sched_barrier after waits)
static __device__ __forceinline__ void bar_lgkm() {
    asm volatile("s_waitcnt lgkmcnt(0)" ::: "memory");
    __builtin_amdgcn_sched_barrier(0);
    __builtin_amdgcn_s_barrier();
    __builtin_amdgcn_sched_barrier(0);
}
static __device__ __forceinline__ void wait_vm0() {
    asm volatile("s_waitcnt vmcnt(0)" ::: "memory");
    __builtin_amdgcn_sched_barrier(0);
}

// fp32 -> bf16 bulk convert (n multiple of 8; one 8-elt group per thread)
__global__ __launch_bounds__(256) void cvt_f2b(const float* __restrict__ in,
                                               u16* __restrict__ out, int n8) {
    int i = blockIdx.x * 256 + threadIdx.x;
    if (i >= n8) return;
    float t[8];
    float4 a = *(const float4*)(in + (size_t)i * 8);
    float4 b = *(const float4*)(in + (size_t)i * 8 + 4);
    t[0] = a.x; t[1] = a.y; t[2] = a.z; t[3] = a.w;
    t[4] = b.x; t[5] = b.y; t[6] = b.z; t[7] = b.w;
    b8st(t, out + (size_t)i * 8);
}

// ---------------------------------------------------------------------------
// 256x256-tile double-buffered 2-phase MFMA GEMM (unchanged from round 9).
// ---------------------------------------------------------------------------
template <typename TC>
__global__ __launch_bounds__(512) void gemm_bt_async(const u16* __restrict__ A,
                                                     const u16* __restrict__ Bm,
                                                     TC* __restrict__ Cm,
                                                     int M, int N, int K) {
    __shared__ __align__(16) u16 sA[2][256 * 64];
    __shared__ __align__(16) u16 sB[2][256 * 64];
    const int tid = threadIdx.x;
    const int w = tid >> 6, lane = tid & 63, lq = lane >> 4, ln = lane & 15;
    const int wm = w >> 2, wn = w & 3;
    const int nx = gridDim.x;
    const int lin = blockIdx.y * nx + blockIdx.x;
    const int chunk = (nx * gridDim.y) >> 3;
    const int wg = (lin & 7) * chunk + (lin >> 3);
    const int mbase = (wg / nx) * 256, nbase = (wg % nx) * 256;

    f32x4 acc[8][4];
#pragma unroll
    for (int mt = 0; mt < 8; mt++)
#pragma unroll
        for (int nt = 0; nt < 4; nt++) acc[mt][nt] = (f32x4){0.f, 0.f, 0.f, 0.f};

    auto stage = [&](int kt, int p) {
        const int k0 = kt * 64;
#pragma unroll
        for (int j = 0; j < 4; j++) {
            int c = tid + 512 * j;                 // chunk 0..2047
            int row = c >> 3;
            int oct = (c & 7) ^ (row & 7);         // swizzled source octet
            async16(A + (size_t)(mbase + row) * K + k0 + oct * 8, &sA[p][c * 8]);
            async16(Bm + (size_t)(nbase + row) * K + k0 + oct * 8, &sB[p][c * 8]);
        }
    };

    const int NT = K >> 6;
    stage(0, 0);
    wait_vm0();
    __builtin_amdgcn_s_barrier();
    __builtin_amdgcn_sched_barrier(0);

    for (int t = 0; t < NT; t++) {
        const int p = t & 1;
        if (t + 1 < NT) stage(t + 1, p ^ 1);       // prefetch overlaps compute
        __builtin_amdgcn_s_setprio(1);
#pragma unroll
        for (int ks = 0; ks < 2; ks++) {
            const int o = ks * 4 + lq;
            bf16x8 bfr[4];
#pragma unroll
            for (int nt = 0; nt < 4; nt++) {
                int nn = wn * 64 + nt * 16 + ln;
                bfr[nt] = *(const bf16x8*)&sB[p][(nn << 6) + ((o ^ (nn & 7)) << 3)];
            }
#pragma unroll
            for (int mt = 0; mt < 8; mt++) {
                int m = wm * 128 + mt * 16 + ln;
                bf16x8 af = *(const bf16x8*)&sA[p][(m << 6) + ((o ^ (m & 7)) << 3)];
#pragma unroll
                for (int nt = 0; nt < 4; nt++)
                    acc[mt][nt] = MFMA16(af, bfr[nt], acc[mt][nt]);
            }
        }
        __builtin_amdgcn_s_setprio(0);
        if (t + 1 < NT) {
            wait_vm0();        // next tile arrived (hidden under the MFMAs)
            bar_lgkm();        // all waves done reading buf p; next tile visible
        }
    }
#pragma unroll
    for (int mt = 0; mt < 8; mt++)
#pragma unroll
        for (int nt = 0; nt < 4; nt++) {
            int col = nbase + wn * 64 + nt * 16 + ln;
#pragma unroll
            for (int r = 0; r < 4; r++) {
                int row = mbase + wm * 128 + mt * 16 + lq * 4 + r;
                cstore(Cm + (size_t)row * N + col, acc[mt][nt][r]);
            }
        }
}

// ---------------------------------------------------------------------------
// Causal depthwise conv (KW=4) + SiLU + optional L2 norm over Dh.
// ---------------------------------------------------------------------------
__global__ __launch_bounds__(256) void conv_silu_norm(const u16* __restrict__ pre,
                                                      const float* __restrict__ w,
                                                      u16* __restrict__ out, int mode) {
    int wid = blockIdx.x * 4 + (threadIdx.x >> 6);
    int lane = threadIdx.x & 63;
    int l = wid & (L_ - 1);
    int bh = wid >> 12;
    int b = bh >> 4, h = bh & 15;

    float vals[2];
    float sumsq = 0.0f;
#pragma unroll
    for (int s = 0; s < 2; s++) {
        int d = lane + 64 * s;
        int c = h * DH + d;
        const u16* col = pre + (size_t)b * L_ * HD + c;
        float acc = 0.0f;
        if (l >= 3) {
            acc = w[c * 4 + 0] * b2f(col[(size_t)(l - 3) * HD]) +
                  w[c * 4 + 1] * b2f(col[(size_t)(l - 2) * HD]) +
                  w[c * 4 + 2] * b2f(col[(size_t)(l - 1) * HD]) +
                  w[c * 4 + 3] * b2f(col[(size_t)l * HD]);
        } else {
#pragma unroll
            for (int j = 0; j < 4; j++) {
                int ll = l - 3 + j;
                if (ll >= 0) acc += w[c * 4 + j] * b2f(col[(size_t)ll * HD]);
            }
        }
        float y = acc * sigm(acc);
        vals[s] = y;
        sumsq += y * y;
    }
    if (mode < 2) {
#pragma unroll
        for (int m = 32; m >= 1; m >>= 1) sumsq += __shfl_xor(sumsq, m, 64);
        float scale = 1.0f / fmaxf(sqrtf(sumsq), 1e-12f);
        if (mode == 0) scale *= 0.08838834764831843f;
        vals[0] *= scale;
        vals[1] *= scale;
    }
    u16* o = out + ((size_t)bh * L_ + l) * DH;
    o[lane] = f2b(vals[0]);
    o[lane + 64] = f2b(vals[1]);
}

// 4 rows per block (4 independent waves) — same per-wave code as before.
__global__ __launch_bounds__(256) void proj_small(const float* __restrict__ x,
                                                  const float* __restrict__ Wb,
                                                  const float* __restrict__ Wa,
                                                  float* __restrict__ bpre,
                                                  float* __restrict__ apre) {
    int row = blockIdx.x * 4 + (threadIdx.x >> 6);
    int lane = threadIdx.x & 63;
    const float* xr = x + (size_t)row * D_;
    float xv[32];
#pragma unroll
    for (int j = 0; j < 32; j++) xv[j] = xr[lane + 64 * j];
    for (int h = 0; h < 16; h++) {
        const float* wr = Wb + (size_t)h * D_;
        float acc = 0.0f;
#pragma unroll
        for (int j = 0; j < 32; j++) acc += xv[j] * wr[lane + 64 * j];
#pragma unroll
        for (int m = 32; m >= 1; m >>= 1) acc += __shfl_xor(acc, m, 64);
        if (lane == 0) bpre[(size_t)row * 16 + h] = acc;
    }
    for (int h = 0; h < 16; h++) {
        const float* wr = Wa + (size_t)h * D_;
        float acc = 0.0f;
#pragma unroll
        for (int j = 0; j < 32; j++) acc += xv[j] * wr[lane + 64 * j];
#pragma unroll
        for (int m = 32; m >= 1; m >>= 1) acc += __shfl_xor(acc, m, 64);
        if (lane == 0) apre[(size_t)row * 16 + h] = acc;
    }
}

__global__ __launch_bounds__(256) void beta_g_k(const float* __restrict__ bpre,
                                                const float* __restrict__ apre,
                                                const float* __restrict__ A_log,
                                                const float* __restrict__ dt_bias,
                                                float* __restrict__ beta, float* __restrict__ g) {
    int gi = blockIdx.x * 256 + threadIdx.x;
    int l = gi & (L_ - 1);
    int bh = gi >> 12;
    int b = bh >> 4, h = bh & 15;
    float bp = bpre[((size_t)b * L_ + l) * 16 + h];
    float ap = apre[((size_t)b * L_ + l) * 16 + h] + dt_bias[h];
    float sp = (ap > 20.0f) ? ap : log1pf(expf(ap));
    beta[(size_t)bh * L_ + l] = 1.0f / (1.0f + expf(-bp));
    g[(size_t)bh * L_ + l] = -expf(A_log[h]) * sp;
}

// ---------------------------------------------------------------------------
// Per-chunk prep (2048 blocks, 4 waves). Unchanged from round 8.
// ---------------------------------------------------------------------------
__global__ __launch_bounds__(256) void prep_chunks(u16* __restrict__ q, u16* __restrict__ k,
                                                   u16* __restrict__ v,
                                                   const float* __restrict__ beta,
                                                   const float* __restrict__ g,
                                                   u16* __restrict__ Wm, u16* __restrict__ W2,
                                                   float* __restrict__ gamC) {
    __shared__ __align__(16) u16 sKb[64 * 136];   // raw K (bf16) -> later V
    __shared__ __align__(16) float sA[64 * 65];   // masked A -> later VsT (u16 128x64)
    __shared__ __align__(16) float sT[64 * 68];   // T fp32 -> later Thi/Tlo (u16 2x4096)
    __shared__ __align__(16) u16 sKsT[128 * 64];  // βγK^T, octet-swizzled
    __shared__ float sLg[CH], sGam[CH], sGcr[CH], sBeta[CH];

    u16* sVsT = (u16*)sA;                          // alias (dead after P2b)
    u16* sThi = (u16*)sT;                          // alias (after snapshot)
    u16* sTlo = (u16*)sT + 4096;

    const int cid = blockIdx.x;
    const int bh = cid >> 6, n = cid & 63;
    const int tid = threadIdx.x;
    const int w = tid >> 6, lane = tid & 63, lq = lane >> 4, ln = lane & 15;
    const size_t cbase = ((size_t)bh * L_ + (size_t)n * CH) * DH;
    u16* qw = q + cbase;
    u16* kw = k + cbase;
    u16* vc = v + cbase;

    // ---- P0: Q fragment prefetch + K staging + cumsum ----
    bf16x8 aQ[4];
    {
        const u16* qrow = qw + (size_t)(w * 16 + ln) * DH;
#pragma unroll
        for (int ks = 0; ks < 4; ks++)
            aQ[ks] = *(const bf16x8*)(qrow + ks * 32 + lq * 8);
    }
#pragma unroll
    for (int rep = 0; rep < 4; rep++) {
        int f = tid + 256 * rep;                   // 1024 chunks of 8 u16
        int row = f >> 4, c8 = (f & 15) * 8;
        *(uint4*)&sKb[row * 136 + c8] = *(const uint4*)(kw + (size_t)row * DH + c8);
    }
    if (tid < 64) {
        float lg = g[(size_t)bh * L_ + (size_t)n * CH + tid];
#pragma unroll
        for (int off = 1; off < 64; off <<= 1) {
            float u = __shfl_up(lg, off, 64);
            if (tid >= off) lg += u;
        }
        float lgC = __shfl(lg, 63, 64);
        sLg[tid] = lg;
        sGam[tid] = expf(lg);
        sGcr[tid] = expf(lgC - lg);
        sBeta[tid] = beta[(size_t)bh * L_ + (size_t)n * CH + tid];
        if (tid == 63) gamC[cid] = expf(lgC);
    }
    __syncthreads();

    // ---- P1: MFMA A/Qd + mask/write; zero sT ----
    {
        f32x4 accA[4], accQ[4];
#pragma unroll
        for (int nt = 0; nt < 4; nt++) {
            accA[nt] = (f32x4){0.f, 0.f, 0.f, 0.f};
            accQ[nt] = (f32x4){0.f, 0.f, 0.f, 0.f};
        }
#pragma unroll
        for (int ks = 0; ks < 4; ks++) {
            int k0 = ks * 32 + lq * 8;
            bf16x8 aK = *(const bf16x8*)&sKb[(w * 16 + ln) * 136 + k0];
#pragma unroll
            for (int nt = 0; nt < 4; nt++) {
                bf16x8 bK = *(const bf16x8*)&sKb[(nt * 16 + ln) * 136 + k0];
                accA[nt] = MFMA16(aK, bK, accA[nt]);
                accQ[nt] = MFMA16(aQ[ks], bK, accQ[nt]);
            }
        }
        for (int idx = tid; idx < 64 * 68; idx += 256) sT[idx] = 0.f;
        u16* w2c = W2 + (size_t)cid * CH * CH;
#pragma unroll
        for (int nt = 0; nt < 4; nt++) {
            int j = nt * 16 + ln;
            float lgj = sLg[j];
#pragma unroll
            for (int r = 0; r < 4; r++) {
                int i = w * 16 + lq * 4 + r;
                float dexp = expf(fminf(sLg[i] - lgj, 0.f));  // valid for j<=i; clamped else
                sA[i * 65 + j] = (j < i) ? sBeta[i] * dexp * accA[nt][r] : 0.f;
                w2c[i * CH + j] = f2b((j <= i) ? accQ[nt][r] * dexp : 0.f);
            }
        }
    }
    __syncthreads();

    // ---- P2a: per-wave diagonal 16x16 inversion (registers) + q scale + KdT ----
    float colv[16];   // lane ln holds column ln of Dinv for wave w's block
    {
        const int i0 = w * 16;
        colv[0] = (ln == 0) ? 1.f : 0.f;
#pragma unroll
        for (int i = 1; i < 16; i++) {
            float acc = (ln == i) ? 1.f : 0.f;
#pragma unroll
            for (int kk = 0; kk < 15; kk++) {
                if (kk < i) acc -= sA[(i0 + i) * 65 + i0 + kk] * colv[kk];
            }
            colv[i] = acc;
        }
    }
#pragma unroll
    for (int rep = 0; rep < 4; rep++) {            // q *= γ (global RMW)
        int f = tid + 256 * rep;
        int i = f >> 4, d8 = (f & 15) * 8;
        float tq[8];
        b8ld(qw + (size_t)i * DH + d8, tq);
        float sq = sGam[i];
#pragma unroll
        for (int jj = 0; jj < 8; jj++) tq[jj] *= sq;
        b8st(tq, qw + (size_t)i * DH + d8);
    }
    // KdT: k chunk region rewritten in place as [e=0..127][i-octets swizzled].
    {
        int e = tid >> 1, qh = tid & 1;
#pragma unroll
        for (int oo = 0; oo < 4; oo++) {
            int i0 = qh * 32 + oo * 8;
            u16 op[8];
#pragma unroll
            for (int jj = 0; jj < 8; jj++)
                op[jj] = f2b(b2f(sKb[(i0 + jj) * 136 + e]) * sGcr[i0 + jj]);
            int slot = ((i0 >> 3) ^ (e & 7));
            uint4 pk;
            pk.x = (unsigned)op[0] | ((unsigned)op[1] << 16);
            pk.y = (unsigned)op[2] | ((unsigned)op[3] << 16);
            pk.z = (unsigned)op[4] | ((unsigned)op[5] << 16);
            pk.w = (unsigned)op[6] | ((unsigned)op[7] << 16);
            *(uint4*)(kw + e * 64 + slot * 8) = pk;
        }
    }
    if (lq == 0) {
#pragma unroll
        for (int i = 0; i < 16; i++) sT[(w * 16 + i) * 68 + w * 16 + ln] = colv[i];
    }
    __syncthreads();

    // ---- P2b: blocked forward substitution, T_ij = -Dinv_i * sum A_ik T_kj ----
    auto trijob = [&](int bi, int bj) {
        float accv[4] = {0.f, 0.f, 0.f, 0.f};      // Ssum[lq*4+r][ln]
        for (int kb = bj; kb < bi; kb++) {
#pragma unroll
            for (int kk = 0; kk < 16; kk++) {
                float bv = sT[(kb * 16 + kk) * 68 + bj * 16 + ln];
#pragma unroll
                for (int r = 0; r < 4; r++)
                    accv[r] += sA[(bi * 16 + lq * 4 + r) * 65 + kb * 16 + kk] * bv;
            }
        }
        float xv[4] = {0.f, 0.f, 0.f, 0.f};
#pragma unroll
        for (int kk = 0; kk < 16; kk++) {
            // Ssum[kk][ln] lives in lane (kk>>2)*16+ln, register kk&3
            float bv = __shfl(accv[kk & 3], (kk >> 2) * 16 + ln, 64);
#pragma unroll
            for (int r = 0; r < 4; r++)
                xv[r] -= sT[(bi * 16 + lq * 4 + r) * 68 + bi * 16 + kk] * bv;
        }
#pragma unroll
        for (int r = 0; r < 4; r++)
            sT[(bi * 16 + lq * 4 + r) * 68 + bj * 16 + ln] = xv[r];
    };
    if (w < 3) trijob(w + 1, w);
    __syncthreads();
    if (w < 2) trijob(w + 2, w);
    __syncthreads();
    if (w == 0) trijob(3, 0);
    __syncthreads();

    // ---- P3 (MFMA): Wm = T @ (βγK), U = T @ (βV) ----
    // (a) KsT[e][kk] = β[kk]γ[kk]K[kk][e], octet-swizzled rows (stride 64)
    {
        int e = tid >> 1, qh = tid & 1;
#pragma unroll
        for (int oo = 0; oo < 4; oo++) {
            int i0 = qh * 32 + oo * 8;
            u16 op[8];
#pragma unroll
            for (int jj = 0; jj < 8; jj++) {
                int kkw = i0 + jj;
                op[jj] = f2b(b2f(sKb[kkw * 136 + e]) * (sBeta[kkw] * sGam[kkw]));
            }
            int slot = ((i0 >> 3) ^ (e & 7));
            uint4 pk;
            pk.x = (unsigned)op[0] | ((unsigned)op[1] << 16);
            pk.y = (unsigned)op[2] | ((unsigned)op[3] << 16);
            pk.z = (unsigned)op[4] | ((unsigned)op[5] << 16);
            pk.w = (unsigned)op[6] | ((unsigned)op[7] << 16);
            *(uint4*)&sKsT[e * 64 + slot * 8] = pk;
        }
    }
    // (b) snapshot T rows to registers (16 f32/thread) before in-place cvt
    float tvs[16];
    {
        int ti = tid >> 2, kks = (tid & 3) * 16;
#pragma unroll
        for (int j = 0; j < 16; j++) tvs[j] = sT[ti * 68 + kks + j];
    }
    __syncthreads();   // KsT built (sKb reads done); all sT reads done

    // (c) write Thi/Tlo (octet-swizzled, stride 64) into sT's space
    {
        int ti = tid >> 2, kks = (tid & 3) * 16;
#pragma unroll
        for (int h = 0; h < 2; h++) {
            u16 hi8[8], lo8[8];
#pragma unroll
            for (int j = 0; j < 8; j++) {
                float tv = tvs[h * 8 + j];
                u16 hb = f2b(tv);
                hi8[j] = hb;
                lo8[j] = f2b(tv - b2f(hb));
            }
            int io = (kks >> 3) + h;
            int slot = io ^ (ti & 7);
            uint4 ph, pl;
            ph.x = (unsigned)hi8[0] | ((unsigned)hi8[1] << 16);
            ph.y = (unsigned)hi8[2] | ((unsigned)hi8[3] << 16);
            ph.z = (unsigned)hi8[4] | ((unsigned)hi8[5] << 16);
            ph.w = (unsigned)hi8[6] | ((unsigned)hi8[7] << 16);
            pl.x = (unsigned)lo8[0] | ((unsigned)lo8[1] << 16);
            pl.y = (unsigned)lo8[2] | ((unsigned)lo8[3] << 16);
            pl.z = (unsigned)lo8[4] | ((unsigned)lo8[5] << 16);
            pl.w = (unsigned)lo8[6] | ((unsigned)lo8[7] << 16);
            *(uint4*)&sThi[ti * 64 + slot * 8] = ph;
            *(uint4*)&sTlo[ti * 64 + slot * 8] = pl;
        }
    }
    // (d) stage V rows into sKb's space (K is dead now)
#pragma unroll
    for (int rep = 0; rep < 4; rep++) {
        int f = tid + 256 * rep;
        int row = f >> 4, c8 = (f & 15) * 8;
        *(uint4*)&sKb[row * 136 + c8] = *(const uint4*)(vc + (size_t)row * DH + c8);
    }
    __syncthreads();   // Thi/Tlo + V staged

    // (e) VsT[e][kk] = β[kk]V[kk][e] into sA's space
    {
        int e = tid >> 1, qh = tid & 1;
#pragma unroll
        for (int oo = 0; oo < 4; oo++) {
            int i0 = qh * 32 + oo * 8;
            u16 op[8];
#pragma unroll
            for (int jj = 0; jj < 8; jj++) {
                int kkw = i0 + jj;
                op[jj] = f2b(b2f(sKb[kkw * 136 + e]) * sBeta[kkw]);
            }
            int slot = ((i0 >> 3) ^ (e & 7));
            uint4 pk;
            pk.x = (unsigned)op[0] | ((unsigned)op[1] << 16);
            pk.y = (unsigned)op[2] | ((unsigned)op[3] << 16);
            pk.z = (unsigned)op[4] | ((unsigned)op[5] << 16);
            pk.w = (unsigned)op[6] | ((unsigned)op[7] << 16);
            *(uint4*)&sVsT[e * 64 + slot * 8] = pk;
        }
    }
    __syncthreads();

    // (f) MFMA: wave w owns output cols e in [w*32, w*32+32)
    {
        u16* wmc = Wm + (size_t)cid * CH * DH;
        bf16x8 bK[2][2], bV[2][2];   // [et][ks]
#pragma unroll
        for (int et = 0; et < 2; et++) {
            int eb = w * 32 + et * 16 + ln;
#pragma unroll
            for (int ks = 0; ks < 2; ks++) {
                int o = ks * 4 + lq;
                bK[et][ks] = *(const bf16x8*)&sKsT[eb * 64 + ((o ^ (eb & 7)) << 3)];
                bV[et][ks] = *(const bf16x8*)&sVsT[eb * 64 + ((o ^ (eb & 7)) << 3)];
            }
        }
#pragma unroll
        for (int it = 0; it < 4; it++) {
            int ia = it * 16 + ln;
            bf16x8 ahi[2], alo[2];
#pragma unroll
            for (int ks = 0; ks < 2; ks++) {
                int o = ks * 4 + lq;
                ahi[ks] = *(const bf16x8*)&sThi[ia * 64 + ((o ^ (ia & 7)) << 3)];
                alo[ks] = *(const bf16x8*)&sTlo[ia * 64 + ((o ^ (ia & 7)) << 3)];
            }
#pragma unroll
            for (int et = 0; et < 2; et++) {
                f32x4 aK = (f32x4){0.f, 0.f, 0.f, 0.f};
                f32x4 aV = (f32x4){0.f, 0.f, 0.f, 0.f};
#pragma unroll
                for (int ks = 0; ks < 2; ks++) {
                    aK = MFMA16(ahi[ks], bK[et][ks], aK);
                    aK = MFMA16(alo[ks], bK[et][ks], aK);
                    aV = MFMA16(ahi[ks], bV[et][ks], aV);
                    aV = MFMA16(alo[ks], bV[et][ks], aV);
                }
                int ecol = w * 32 + et * 16 + ln;
#pragma unroll
                for (int r = 0; r < 4; r++) {
                    int irow = it * 16 + lq * 4 + r;
                    wmc[(size_t)irow * DH + ecol] = f2b(aK[r]);
                    vc[(size_t)irow * DH + ecol] = f2b(aV[r]);
                }
            }
        }
    }
}

// ---------------------------------------------------------------------------
// MFMA inter-chunk scan (256 blocks = BH * 8 d-groups of 16), round-9
// structure with phase-A interleave: G1 (Wm@S^T) and G2a (Qd@S^T) share
// the sS fragment loads and run as dual independent MFMA chains.
// ---------------------------------------------------------------------------
__global__ __launch_bounds__(256) void scan_mfma(const u16* __restrict__ Wm,
                                                 const u16* __restrict__ U,
                                                 const u16* __restrict__ Qd,
                                                 const u16* __restrict__ Kd,
                                                 const u16* __restrict__ W2,
                                                 const float* __restrict__ gamC,
                                                 const float* __restrict__ S0,
                                                 float* __restrict__ Og,
                                                 float* __restrict__ Sfin) {
    __shared__ __align__(16) u16 sWm[2][64 * 128];
    __shared__ __align__(16) u16 sQd[2][64 * 128];
    __shared__ __align__(16) u16 sW2[2][64 * 64];
    __shared__ __align__(16) u16 sKdT[2][128 * 64];
    __shared__ __align__(16) u16 sS[2][16 * 136];
    __shared__ __align__(16) u16 sMidT[16 * 72];

    const int bid = blockIdx.x;
    // XCD swizzle: 8 dg-blocks of one head share bid%8 (one XCD's L2)
    const int xcd = bid & 7, slot = bid >> 3;
    const int bh = xcd + 8 * (slot >> 3), dg = slot & 7, d0 = dg * 16;
    const int tid = threadIdx.x;
    const int w = tid >> 6, lane = tid & 63, lq = lane >> 4, ln = lane & 15;

    f32x4 S_t[2];
#pragma unroll
    for (int t2 = 0; t2 < 2; t2++)
#pragma unroll
        for (int r = 0; r < 4; r++)
            S_t[t2][r] = S0[(size_t)bh * DH * DH + (size_t)(d0 + lq * 4 + r) * DH + w * 32 + t2 * 16 + ln];

    // async stage of chunk m tiles into buffer p (Wm, Qd, W2, KdT)
    auto stage_async = [&](int m, int p) {
        const size_t cid2 = (size_t)bh * NCH + m;
        const u16* wmc = Wm + cid2 * CH * DH;
        const size_t tb = ((size_t)bh * L_ + (size_t)m * CH) * DH;
        const u16* qc  = Qd + tb;
        const u16* kc  = Kd + tb;                  // pre-transposed+swizzled
        const u16* w2c = W2 + cid2 * CH * CH;
#pragma unroll
        for (int j = 0; j < 4; j++) {
            int c = tid + 256 * j;                  // 16B chunk 0..1023
            int row = c >> 4;
            int osrc = (c & 15) ^ (row & 7);        // pre-swizzled source octet
            async16(wmc + (size_t)row * DH + osrc * 8, &sWm[p][c * 8]);
            async16(qc  + (size_t)row * DH + osrc * 8, &sQd[p][c * 8]);
            async16(kc + (size_t)c * 8, &sKdT[p][c * 8]);   // linear copy
        }
#pragma unroll
        for (int j = 0; j < 2; j++) {
            int c = tid + 256 * j;                  // 0..511
            int row = c >> 3;
            int osrc = (c & 7) ^ (row & 7);
            async16(w2c + (size_t)row * CH + osrc * 8, &sW2[p][c * 8]);
        }
    };
    auto write_ss = [&](int p) {
#pragma unroll
        for (int t2 = 0; t2 < 2; t2++)
#pragma unroll
            for (int r = 0; r < 4; r++)
                sS[p][(lq * 4 + r) * 136 + w * 32 + t2 * 16 + ln] = f2b(S_t[t2][r]);
    };

    u16 ureg[4], uregN[4];
    auto load_ureg = [&](int m, u16* dst) {
        const u16* uc = U + ((size_t)bh * L_ + (size_t)m * CH) * DH;
#pragma unroll
        for (int r = 0; r < 4; r++)
            dst[r] = uc[(size_t)(w * 16 + lq * 4 + r) * DH + d0 + ln];
    };

    // ---- prologue: chunk 0 into buffer 0 ----
    stage_async(0, 0);
    load_ureg(0, ureg);
    float gCur = gamC[(size_t)bh * NCH];
    float gNext = 0.f;
    write_ss(0);
    wait_vm0();
    bar_lgkm();

    for (int n = 0; n < NCH; n++) {
        const int p = n & 1;
        const bool hasN = (n + 1 < NCH);
        if (hasN) {
            stage_async(n + 1, p ^ 1);
            load_ureg(n + 1, uregN);
            gNext = gamC[(size_t)bh * NCH + n + 1];
        }

        // Phase A: G1 (mid = U - Wm@S^T) and G2a (Qd@S^T), interleaved —
        // independent accumulator chains sharing the sS fragment loads.
        f32x4 oacc = (f32x4){0.f, 0.f, 0.f, 0.f};
        {
            f32x4 macc = (f32x4){0.f, 0.f, 0.f, 0.f};
            const int i = w * 16 + ln;
#pragma unroll
            for (int ks = 0; ks < 4; ks++) {
                int o = ks * 4 + lq;
                bf16x8 aW = *(const bf16x8*)&sWm[p][i * 128 + ((o ^ (i & 7)) << 3)];
                bf16x8 aQ = *(const bf16x8*)&sQd[p][i * 128 + ((o ^ (i & 7)) << 3)];
                bf16x8 b  = *(const bf16x8*)&sS[p][ln * 136 + ks * 32 + lq * 8];
                macc = MFMA16(aW, b, macc);
                oacc = MFMA16(aQ, b, oacc);
            }
#pragma unroll
            for (int r = 0; r < 4; r++) {
                int ii = w * 16 + lq * 4 + r;
                float mv = b2f(ureg[r]) - macc[r];
                sMidT[ln * 72 + ii] = f2b(mv);
            }
        }
        bar_lgkm();   // lgkm-only: async prefetch stays in flight

        // Phase B: G2b (oacc += W2@mid) + store; G3 state update.
        {
            const int i = w * 16 + ln;
#pragma unroll
            for (int ks = 0; ks < 2; ks++) {
                int o = ks * 4 + lq;
                bf16x8 a = *(const bf16x8*)&sW2[p][i * 64 + ((o ^ (i & 7)) << 3)];
                bf16x8 b = *(const bf16x8*)&sMidT[ln * 72 + ks * 32 + lq * 8];
                oacc = MFMA16(a, b, oacc);
            }
#pragma unroll
            for (int r = 0; r < 4; r++) {
                int ii = w * 16 + lq * 4 + r;
                Og[((size_t)bh * L_ + (size_t)n * CH + ii) * DH + d0 + ln] = oacc[r];
            }
        }

        // G3: S = gC*S + mid^T @ Kd
#pragma unroll
        for (int t2 = 0; t2 < 2; t2++)
#pragma unroll
            for (int r = 0; r < 4; r++) S_t[t2][r] *= gCur;
#pragma unroll
        for (int ks = 0; ks < 2; ks++) {
            bf16x8 a = *(const bf16x8*)&sMidT[ln * 72 + ks * 32 + lq * 8];
#pragma unroll
            for (int t2 = 0; t2 < 2; t2++) {
                int e = (2 * w + t2) * 16 + ln;
                int o = ks * 4 + lq;
                bf16x8 b = *(const bf16x8*)&sKdT[p][e * 64 + ((o ^ (e & 7)) << 3)];
                S_t[t2] = MFMA16(a, b, S_t[t2]);
            }
        }

        if (hasN) {
            write_ss(p ^ 1);         // ds writes overlap the vm drain below
#pragma unroll
            for (int r = 0; r < 4; r++) ureg[r] = uregN[r];
            gCur = gNext;
            wait_vm0();              // staged tiles + ureg arrived
            bar_lgkm();              // next-iter tiles visible to all waves
        }
    }

#pragma unroll
    for (int t2 = 0; t2 < 2; t2++)
#pragma unroll
        for (int r = 0; r < 4; r++)
            Sfin[(size_t)bh * DH * DH + (size_t)(d0 + lq * 4 + r) * DH + w * 32 + t2 * 16 + ln] = S_t[t2][r];
}

__global__ __launch_bounds__(256) void epilogue_gate(const float* __restrict__ Ob,
                                                     const u16* __restrict__ gpre,
                                                     const float* __restrict__ norm_w,
                                                     u16* __restrict__ gated) {
    int wid = blockIdx.x * 4 + (threadIdx.x >> 6);
    int lane = threadIdx.x & 63;
    int l = wid & (L_ - 1);
    int bh = wid >> 12;
    int b = bh >> 4, h = bh & 15;
    const float* orow = Ob + ((size_t)bh * L_ + l) * DH;
    float o0 = orow[lane], o1 = orow[lane + 64];
    float ss = o0 * o0 + o1 * o1;
#pragma unroll
    for (int m = 32; m >= 1; m >>= 1) ss += __shfl_xor(ss, m, 64);
    float r = rsqrtf(ss * (1.0f / 128.0f) + 1e-5f);
    size_t gidx = ((size_t)b * L_ + l) * HD + h * DH;
    float gp0 = b2f(gpre[gidx + lane]), gp1 = b2f(gpre[gidx + lane + 64]);
    gated[gidx + lane] = f2b(o0 * r * norm_w[lane] * (gp0 * sigm(gp0)));
    gated[gidx + lane + 64] = f2b(o1 * r * norm_w[lane + 64] * (gp1 * sigm(gp1)));
}

// ---------------------------------------------------------------------------
extern "C" void kernel_launch(void* const* d_in, const int* in_sizes, int n_in,
                              void* d_out, int out_size, void* d_ws, size_t ws_size,
                              hipStream_t stream) {
    const float* x       = (const float*)d_in[0];
    const float* Wq      = (const float*)d_in[1];
    const float* Wk      = (const float*)d_in[2];
    const float* Wv      = (const float*)d_in[3];
    const float* Wb      = (const float*)d_in[4];
    const float* Wa      = (const float*)d_in[5];
    const float* A_log   = (const float*)d_in[6];
    const float* dt_bias = (const float*)d_in[7];
    const float* conv_q  = (const float*)d_in[8];
    const float* conv_k  = (const float*)d_in[9];
    const float* conv_v  = (const float*)d_in[10];
    const float* Wg      = (const float*)d_in[11];
    const float* norm_w  = (const float*)d_in[12];
    const float* Wo      = (const float*)d_in[13];
    const float* S0      = (const float*)d_in[14];
    float* out = (float*)d_out;

    // Workspace (~195 MB, u16 units):
    //   Pb (preact scratch -> Wm), Qb (q->Qd), Kb (k->KdT -> gated),
    //   Vb (v->U -> gpre), W2b, xb (bf16 x), wbuf (rotating bf16 weight).
    // O (fp32) lives in d_out[0:PSZ]; Sfin in d_out[PSZ:].
    u16* Pb = (u16*)d_ws;
    u16* Qb = Pb + PSZ;
    u16* Kb = Qb + PSZ;
    u16* Vb = Kb + PSZ;
    u16* W2b = Vb + PSZ;                        // PSZ/2 u16
    u16* xb  = W2b + PSZ / 2;                   // PSZ u16
    u16* wbuf = xb + PSZ;                       // 2048*2048 u16
    float* bpre = (float*)(wbuf + 4194304);
    float* apre = bpre + BHL;
    float* betab = apre + BHL;
    float* gbuf = betab + BHL;
    float* gamC = gbuf + BHL;                   // 2048

    float* Obuf = out;
    float* Sfin = out + PSZ;

    dim3 gblk(8, 32);   // (N/256, M/256) for M=8192,N=2048; 256 blocks
    const int W8 = 2048 * 2048 / 8;             // weight cvt groups

    cvt_f2b<<<8192, 256, 0, stream>>>(x, xb, (int)(PSZ / 8));
    cvt_f2b<<<2048, 256, 0, stream>>>(Wq, wbuf, W8);
    gemm_bt_async<u16><<<gblk, 512, 0, stream>>>(xb, wbuf, Pb, 8192, 2048, 2048);
    conv_silu_norm<<<32768, 256, 0, stream>>>(Pb, conv_q, Qb, 0);
    cvt_f2b<<<2048, 256, 0, stream>>>(Wk, wbuf, W8);
    gemm_bt_async<u16><<<gblk, 512, 0, stream>>>(xb, wbuf, Pb, 8192, 2048, 2048);
    conv_silu_norm<<<32768, 256, 0, stream>>>(Pb, conv_k, Kb, 1);
    cvt_f2b<<<2048, 256, 0, stream>>>(Wv, wbuf, W8);
    gemm_bt_async<u16><<<gblk, 512, 0, stream>>>(xb, wbuf, Pb, 8192, 2048, 2048);
    conv_silu_norm<<<32768, 256, 0, stream>>>(Pb, conv_v, Vb, 2);
    proj_small<<<2048, 256, 0, stream>>>(x, Wb, Wa, bpre, apre);
    beta_g_k<<<512, 256, 0, stream>>>(bpre, apre, A_log, dt_bias, betab, gbuf);
    prep_chunks<<<2048, 256, 0, stream>>>(Qb, Kb, Vb, betab, gbuf, Pb, W2b, gamC);
    scan_mfma<<<256, 256, 0, stream>>>(Pb, Vb, Qb, Kb, W2b, gamC, S0, Obuf, Sfin);
    // g projection after the scan: gpre reuses Vb (U is dead now)
    cvt_f2b<<<2048, 256, 0, stream>>>(Wg, wbuf, W8);
    gemm_bt_async<u16><<<gblk, 512, 0, stream>>>(xb, wbuf, Vb, 8192, 2048, 2048);
    epilogue_gate<<<32768, 256, 0, stream>>>(Obuf, Vb, norm_w, Kb);
    cvt_f2b<<<2048, 256, 0, stream>>>(Wo, wbuf, W8);
    gemm_bt_async<float><<<gblk, 512, 0, stream>>>(Kb, wbuf, out, 8192, 2048, 2048);
}